// Round 11
// baseline (134.968 us; speedup 1.0000x reference)
//
#include <hip/hip_runtime.h>

#define B_ 2
#define S_ 2048
#define F_ 1024
#define H_ 16
#define D_ 64

typedef __bf16 bf16x8 __attribute__((ext_vector_type(8)));
typedef float f32x4 __attribute__((ext_vector_type(4)));
typedef float f32x16 __attribute__((ext_vector_type(16)));

union U8 { unsigned int u[4]; bf16x8 v; };

__device__ __forceinline__ unsigned short f2bf(float f) {
    union { float f; unsigned int u; } v;
    v.f = f;
    unsigned int r = v.u + 0x7fffu + ((v.u >> 16) & 1u);
    return (unsigned short)(r >> 16);
}

__device__ __forceinline__ unsigned int cvtpk_bf16(float lo, float hi) {
    unsigned int r;
    asm("v_cvt_pk_bf16_f32 %0, %1, %2" : "=v"(r) : "v"(lo), "v"(hi));
    return r;
}

// cross-half (lane l <-> l^32) reductions. DS-based shfl: proven correct (R4).
__device__ __forceinline__ float xhalf_max(float x) {
    return fmaxf(x, __shfl_xor(x, 32));
}
__device__ __forceinline__ float xhalf_sum(float x) {
    return x + __shfl_xor(x, 32);
}

// async global->LDS, 16B per lane. LDS dest must be wave-uniform base + lane*16.
__device__ __forceinline__ void gload16(const unsigned short* g, unsigned short* l) {
    __builtin_amdgcn_global_load_lds(
        (const __attribute__((address_space(1))) unsigned int*)g,
        (__attribute__((address_space(3))) unsigned int*)l,
        16, 0, 0);
}

// ---------- f32 -> bf16 elementwise convert (vectorized) ----------
__global__ void cvt_kernel(const float* __restrict__ in, unsigned short* __restrict__ out, int n4) {
    int i = blockIdx.x * blockDim.x + threadIdx.x;
    if (i >= n4) return;
    float4 v = reinterpret_cast<const float4*>(in)[i];
    ushort4 o;
    o.x = f2bf(v.x); o.y = f2bf(v.y); o.z = f2bf(v.z); o.w = f2bf(v.w);
    reinterpret_cast<ushort4*>(out)[i] = o;
}

// ---------- f32 [R][C] -> bf16 [C][R] transpose-convert ----------
__global__ void tcvt_kernel(const float* __restrict__ in, unsigned short* __restrict__ out, int R, int C) {
    __shared__ float t[32][33];
    int r0 = blockIdx.y << 5, c0 = blockIdx.x << 5;
    int tx = threadIdx.x, ty = threadIdx.y;
#pragma unroll
    for (int kk = 0; kk < 4; ++kk)
        t[ty + 8 * kk][tx] = in[(size_t)(r0 + ty + 8 * kk) * C + c0 + tx];
    __syncthreads();
#pragma unroll
    for (int kk = 0; kk < 4; ++kk)
        out[(size_t)(c0 + ty + 8 * kk) * R + r0 + tx] = f2bf(t[tx][ty + 8 * kk]);
}

// ---------- GEMM1: qkv = x @ w_attn + b_attn (3-stage pipeline, counted vmcnt) ----------
// q,k stored FRAGMENT-MAJOR: [bh][t=s/32][kf=d/16][lane=(s&31)|((d>>3&1)<<5)][e=d&7]
// v  stored FRAGMENT-MAJOR: [bh][jt=s/32][db=d/32][kf=(s>>4)&1][lane=(d&31)|((s>>3&1)<<5)][e=s&7]
// q pre-scaled by (1/8)*log2(e)
__global__ __launch_bounds__(256) void gemm_qkv(const unsigned short* __restrict__ A,
                                                const unsigned short* __restrict__ Bt,
                                                const float* __restrict__ bias,
                                                unsigned short* __restrict__ qo,
                                                unsigned short* __restrict__ ko,
                                                unsigned short* __restrict__ vo) {
    __shared__ __align__(16) unsigned short As[3 * 128 * 32];  // [buf][row][col]
    __shared__ __align__(16) unsigned short Bs[3 * 128 * 32];
    const int K = 1024, NT = 32;
    int m0 = blockIdx.y << 7, n0 = blockIdx.x << 7;
    int tid = threadIdx.x;
    int w = tid >> 6, l = tid & 63, lg = l >> 4, lr = l & 15;
    int wm = (w >> 1) << 6, wn = (w & 1) << 6;
    f32x4 acc[4][4] = {};

    int sr = tid >> 2, sc = (tid & 3) << 3;
    const unsigned short* Ab = A + (size_t)(m0 + sr) * K + sc;
    const unsigned short* Bb = Bt + (size_t)(n0 + sr) * K + sc;
    const size_t half = (size_t)64 * K;

    // prologue: stage steps 0,1 into buffers 0,1; wait for step 0 (4 loads stay in flight)
    gload16(Ab, &As[tid * 8]);
    gload16(Ab + half, &As[2048 + tid * 8]);
    gload16(Bb, &Bs[tid * 8]);
    gload16(Bb + half, &Bs[2048 + tid * 8]);
    gload16(Ab + 32, &As[4096 + tid * 8]);
    gload16(Ab + 32 + half, &As[4096 + 2048 + tid * 8]);
    gload16(Bb + 32, &Bs[4096 + tid * 8]);
    gload16(Bb + 32 + half, &Bs[4096 + 2048 + tid * 8]);
    asm volatile("s_waitcnt vmcnt(4)" ::: "memory");
    __builtin_amdgcn_s_barrier();

    // invariant at entry of step t: buf[t%3] ready; t+1's 4 loads outstanding
    for (int t = 0; t < NT; ++t) {
        if (t + 2 < NT) {
            int b = ((t + 2) % 3) * 4096;
            int ko2 = (t + 2) * 32;
            gload16(Ab + ko2, &As[b + tid * 8]);
            gload16(Ab + ko2 + half, &As[b + 2048 + tid * 8]);
            gload16(Bb + ko2, &Bs[b + tid * 8]);
            gload16(Bb + ko2 + half, &Bs[b + 2048 + tid * 8]);
        }
        int cb = (t % 3) * 4096;
        bf16x8 af[4], bfr[4];
#pragma unroll
        for (int mi = 0; mi < 4; ++mi)
            af[mi] = *reinterpret_cast<const bf16x8*>(&As[cb + (wm + mi * 16 + lr) * 32 + (lg << 3)]);
#pragma unroll
        for (int ni = 0; ni < 4; ++ni)
            bfr[ni] = *reinterpret_cast<const bf16x8*>(&Bs[cb + (wn + ni * 16 + lr) * 32 + (lg << 3)]);
#pragma unroll
        for (int mi = 0; mi < 4; ++mi)
#pragma unroll
            for (int ni = 0; ni < 4; ++ni)
                acc[mi][ni] = __builtin_amdgcn_mfma_f32_16x16x32_bf16(af[mi], bfr[ni], acc[mi][ni], 0, 0, 0);
        // own t+1 loads landed; t+2's 4 stay in flight across the barrier
        if (t + 2 < NT) asm volatile("s_waitcnt vmcnt(4)" ::: "memory");
        else            asm volatile("s_waitcnt vmcnt(0)" ::: "memory");
        __builtin_amdgcn_s_barrier();
    }
#pragma unroll
    for (int mi = 0; mi < 4; ++mi) {
#pragma unroll
        for (int ni = 0; ni < 4; ++ni) {
            int col = n0 + wn + ni * 16 + lr;
            float bv = bias[col];
            int part = col >> 10, cc = col & 1023, h = cc >> 6, d = cc & 63;
            int row0 = m0 + wm + mi * 16 + (lg << 2);
            int bb = row0 >> 11, s0 = row0 & 2047;
            int bh = bb * H_ + h;
            if (part == 2) {
                int jt = s0 >> 5, db = d >> 5, kf2 = (s0 >> 4) & 1, hi2 = (s0 >> 3) & 1;
                int ll = (d & 31) | (hi2 << 5), e0 = s0 & 7;
                ushort4 pk;
                unsigned short* p = reinterpret_cast<unsigned short*>(&pk);
#pragma unroll
                for (int r = 0; r < 4; ++r) p[r] = f2bf(acc[mi][ni][r] + bv);
                *reinterpret_cast<ushort4*>(
                    &vo[(size_t)((((bh * 64 + jt) * 2 + db) * 2 + kf2)) * 512 + ll * 8 + e0]) = pk;
            } else {
                unsigned short* dst = part == 0 ? qo : ko;
                float scale = part == 0 ? 0.125f * 1.44269504f : 1.0f;
                int t2 = s0 >> 5, kf2 = d >> 4, e = d & 7;
                int lbase = ((d >> 3) & 1) << 5;
                size_t fb = (size_t)((bh * 64 + t2) * 4 + kf2) * 512 + e;
#pragma unroll
                for (int r = 0; r < 4; ++r) {
                    float vv = (acc[mi][ni][r] + bv) * scale;
                    dst[fb + (size_t)((((s0 + r) & 31) | lbase)) * 8] = f2bf(vv);
                }
            }
        }
    }
}

// ---------- GEMM2: out = z @ w_proj + b_proj (f32 out; 3-stage pipeline) ----------
__global__ __launch_bounds__(256) void gemm_proj(const unsigned short* __restrict__ A,
                                                 const unsigned short* __restrict__ Bt,
                                                 const float* __restrict__ bias,
                                                 float* __restrict__ out) {
    __shared__ __align__(16) unsigned short As[3 * 128 * 32];
    __shared__ __align__(16) unsigned short Bs[3 * 128 * 32];
    const int K = 1024, NT = 32;
    int m0 = blockIdx.y << 7, n0 = blockIdx.x << 7;
    int tid = threadIdx.x;
    int w = tid >> 6, l = tid & 63, lg = l >> 4, lr = l & 15;
    int wm = (w >> 1) << 6, wn = (w & 1) << 6;
    f32x4 acc[4][4] = {};

    int sr = tid >> 2, sc = (tid & 3) << 3;
    const unsigned short* Ab = A + (size_t)(m0 + sr) * K + sc;
    const unsigned short* Bb = Bt + (size_t)(n0 + sr) * K + sc;
    const size_t half = (size_t)64 * K;

    gload16(Ab, &As[tid * 8]);
    gload16(Ab + half, &As[2048 + tid * 8]);
    gload16(Bb, &Bs[tid * 8]);
    gload16(Bb + half, &Bs[2048 + tid * 8]);
    gload16(Ab + 32, &As[4096 + tid * 8]);
    gload16(Ab + 32 + half, &As[4096 + 2048 + tid * 8]);
    gload16(Bb + 32, &Bs[4096 + tid * 8]);
    gload16(Bb + 32 + half, &Bs[4096 + 2048 + tid * 8]);
    asm volatile("s_waitcnt vmcnt(4)" ::: "memory");
    __builtin_amdgcn_s_barrier();

    for (int t = 0; t < NT; ++t) {
        if (t + 2 < NT) {
            int b = ((t + 2) % 3) * 4096;
            int ko2 = (t + 2) * 32;
            gload16(Ab + ko2, &As[b + tid * 8]);
            gload16(Ab + ko2 + half, &As[b + 2048 + tid * 8]);
            gload16(Bb + ko2, &Bs[b + tid * 8]);
            gload16(Bb + ko2 + half, &Bs[b + 2048 + tid * 8]);
        }
        int cb = (t % 3) * 4096;
        bf16x8 af[4], bfr[4];
#pragma unroll
        for (int mi = 0; mi < 4; ++mi)
            af[mi] = *reinterpret_cast<const bf16x8*>(&As[cb + (wm + mi * 16 + lr) * 32 + (lg << 3)]);
#pragma unroll
        for (int ni = 0; ni < 4; ++ni)
            bfr[ni] = *reinterpret_cast<const bf16x8*>(&Bs[cb + (wn + ni * 16 + lr) * 32 + (lg << 3)]);
#pragma unroll
        for (int mi = 0; mi < 4; ++mi)
#pragma unroll
            for (int ni = 0; ni < 4; ++ni)
                acc[mi][ni] = __builtin_amdgcn_mfma_f32_16x16x32_bf16(af[mi], bfr[ni], acc[mi][ni], 0, 0, 0);
        if (t + 2 < NT) asm volatile("s_waitcnt vmcnt(4)" ::: "memory");
        else            asm volatile("s_waitcnt vmcnt(0)" ::: "memory");
        __builtin_amdgcn_s_barrier();
    }
#pragma unroll
    for (int mi = 0; mi < 4; ++mi) {
#pragma unroll
        for (int ni = 0; ni < 4; ++ni) {
            int col = n0 + wn + ni * 16 + lr;
            float bv = bias[col];
#pragma unroll
            for (int r = 0; r < 4; ++r) {
                int row = m0 + wm + mi * 16 + (lg << 2) + r;
                out[(size_t)row * F_ + col] = acc[mi][ni][r] + bv;
            }
        }
    }
}

// ---------- attention 32x32 tile: fragment-major loads, in-register softmax ----------
__device__ __forceinline__ void attn_tile32(
    const unsigned short* __restrict__ k, const unsigned short* __restrict__ v,
    int bh, int jt, bool pref, bool diag, int qcol, int hi, size_t lofs,
    const bf16x8 (&qf)[4], bf16x8 (&kcur)[4], bf16x8 (&knxt)[4],
    float &m, float &lsum, f32x16 &ot0, f32x16 &ot1)
{
    // V fragments for THIS tile: contiguous 1KB wave-loads
    bf16x8 vf[4];
    const unsigned short* vp = v + (size_t)(bh * 64 + jt) * 2048 + lofs;
#pragma unroll
    for (int i = 0; i < 4; ++i)
        vf[i] = *reinterpret_cast<const bf16x8*>(vp + i * 512);
    // K fragments for NEXT tile
    if (pref) {
        const unsigned short* kp = k + (size_t)(bh * 64 + jt + 1) * 2048 + lofs;
#pragma unroll
        for (int kf = 0; kf < 4; ++kf)
            knxt[kf] = *reinterpret_cast<const bf16x8*>(kp + kf * 512);
    }

    // S^T[k][q] = K Q^T : lane owns column q=qcol, 16 k-rows in regs
    f32x16 st = {};
#pragma unroll
    for (int kf = 0; kf < 4; ++kf)
        st = __builtin_amdgcn_mfma_f32_32x32x16_bf16(kcur[kf], qf[kf], st, 0, 0, 0);

    // causal mask: only the diagonal tile
    if (diag) {
        int qmh = qcol - 4 * hi;
#pragma unroll
        for (int r = 0; r < 16; ++r) {
            const int kbase = (r & 3) + 8 * (r >> 2);
            st[r] = (kbase > qmh) ? -1e30f : st[r];
        }
    }

    // row max: in-register tree + cross-half exchange
    float pm = st[0];
#pragma unroll
    for (int r = 1; r < 16; ++r) pm = fmaxf(pm, st[r]);
    pm = xhalf_max(pm);

    // defer-max (T13): rescale only when max grows beyond threshold (log2 domain)
    if (!__all(pm <= m + 8.0f)) {
        float mn = fmaxf(m, pm);
        float scl = exp2f(m - mn);
        m = mn;
        lsum *= scl;
        ot0 *= scl;
        ot1 *= scl;
    }

    // exp + lane-local partial sum (cross-half sum deferred to end of wave;
    // partner lanes share qcol hence share m, so deferral is exact)
    float ps = 0.f;
#pragma unroll
    for (int r = 0; r < 16; ++r) { st[r] = exp2f(st[r] - m); ps += st[r]; }
    lsum += ps;

    // pack P -> bf16 B-fragments via cvt_pk + permlane32_swap (T12; proven R4/R5)
    U8 pa0, pa1;
#pragma unroll
    for (int f = 0; f < 2; ++f) {
        unsigned int a0 = cvtpk_bf16(st[f * 8 + 0], st[f * 8 + 1]);
        unsigned int b0 = cvtpk_bf16(st[f * 8 + 4], st[f * 8 + 5]);
        asm("v_permlane32_swap_b32 %0, %1" : "+v"(a0), "+v"(b0));
        unsigned int a1 = cvtpk_bf16(st[f * 8 + 2], st[f * 8 + 3]);
        unsigned int b1 = cvtpk_bf16(st[f * 8 + 6], st[f * 8 + 7]);
        asm("v_permlane32_swap_b32 %0, %1" : "+v"(a1), "+v"(b1));
        U8& pa = f ? pa1 : pa0;
        pa.u[0] = a0; pa.u[1] = a1; pa.u[2] = b0; pa.u[3] = b1;
    }

    // O^T[d][q] += V^T P^T
    ot0 = __builtin_amdgcn_mfma_f32_32x32x16_bf16(vf[0], pa0.v, ot0, 0, 0, 0);
    ot0 = __builtin_amdgcn_mfma_f32_32x32x16_bf16(vf[1], pa1.v, ot0, 0, 0, 0);
    ot1 = __builtin_amdgcn_mfma_f32_32x32x16_bf16(vf[2], pa0.v, ot1, 0, 0, 0);
    ot1 = __builtin_amdgcn_mfma_f32_32x32x16_bf16(vf[3], pa1.v, ot1, 0, 0, 0);
}

// ---------- causal flash attention: 2-wave block, 2-way split-K, LDS merge ----------
__global__ __launch_bounds__(128, 3) void attn_kernel(const unsigned short* __restrict__ q,
                                                      const unsigned short* __restrict__ k,
                                                      const unsigned short* __restrict__ v,
                                                      unsigned short* __restrict__ z) {
    __shared__ __align__(16) float mbuf[64][36];
    int bh = blockIdx.x;
    int qt = gridDim.y - 1 - blockIdx.y;   // longest blocks dispatched first
    int q0 = qt << 5;
    int tid = threadIdx.x, w = tid >> 6, l = tid & 63;
    int qcol = l & 31, hi = l >> 5;
    size_t lofs = (size_t)l * 8;

    bf16x8 qf[4];
    {
        const unsigned short* qp = q + (size_t)(bh * 64 + qt) * 2048 + lofs;
#pragma unroll
        for (int kf = 0; kf < 4; ++kf)
            qf[kf] = *reinterpret_cast<const bf16x8*>(qp + kf * 512);
    }

    f32x16 ot0 = {}, ot1 = {};
    float m = -1e30f, lsum = 0.f;

    // split-K: wave0 -> tiles [0, half), wave1 -> [half, qt] (owns diagonal)
    int ntk = qt + 1;
    int half = ntk >> 1;
    int start = w ? half : 0;
    int end = w ? ntk : half;

    if (start < end) {
        bf16x8 kA[4], kB[4];
        const unsigned short* kp = k + (size_t)(bh * 64 + start) * 2048 + lofs;
#pragma unroll
        for (int kf = 0; kf < 4; ++kf)
            kA[kf] = *reinterpret_cast<const bf16x8*>(kp + kf * 512);

        int jt = start;
        for (;;) {
            attn_tile32(k, v, bh, jt, jt + 1 < end, jt == qt, qcol, hi, lofs,
                        qf, kA, kB, m, lsum, ot0, ot1);
            if (++jt >= end) break;
            attn_tile32(k, v, bh, jt, jt + 1 < end, jt == qt, qcol, hi, lofs,
                        qf, kB, kA, m, lsum, ot0, ot1);
            if (++jt >= end) break;
        }
    }

    // full-row lsum (cross-half halves share m)
    lsum = xhalf_sum(lsum);

    // ---- split-K merge: wave 1 publishes, wave 0 combines + writes ----
    if (w == 1) {
        float* row = mbuf[l];
        row[0] = m;
        row[1] = lsum;
        *reinterpret_cast<f32x16*>(&row[4]) = ot0;
        *reinterpret_cast<f32x16*>(&row[20]) = ot1;
    }
    __syncthreads();
    if (w == 0) {
        float m1 = mbuf[l][0], l1 = mbuf[l][1];
        float mm = fmaxf(m, m1);
        float s0 = exp2f(m - mm), s1 = exp2f(m1 - mm);
        float lt = lsum * s0 + l1 * s1;
        f32x16 t0 = *reinterpret_cast<const f32x16*>(&mbuf[l][4]);
        f32x16 t1 = *reinterpret_cast<const f32x16*>(&mbuf[l][20]);
        ot0 = ot0 * s0 + t0 * s1;
        ot1 = ot1 * s0 + t1 * s1;

        float inv = 1.0f / lt;
        int b = bh >> 4, h = bh & 15;
        size_t zrow = ((size_t)(b * S_ + q0 + qcol)) * F_ + h * D_;
#pragma unroll
        for (int db = 0; db < 2; ++db) {
#pragma unroll
            for (int rq = 0; rq < 4; ++rq) {
                ushort4 pk;
                unsigned short* pp = reinterpret_cast<unsigned short*>(&pk);
#pragma unroll
                for (int i = 0; i < 4; ++i) {
                    float val = (db == 0 ? ot0[rq * 4 + i] : ot1[rq * 4 + i]) * inv;
                    pp[i] = f2bf(val);
                }
                *reinterpret_cast<ushort4*>(&z[zrow + db * 32 + rq * 8 + hi * 4]) = pk;
            }
        }
    }
}

extern "C" void kernel_launch(void* const* d_in, const int* in_sizes, int n_in,
                              void* d_out, int out_size, void* d_ws, size_t ws_size,
                              hipStream_t stream) {
    const float* x      = (const float*)d_in[0];
    const float* w_attn = (const float*)d_in[1];
    const float* b_attn = (const float*)d_in[2];
    const float* w_proj = (const float*)d_in[3];
    const float* b_proj = (const float*)d_in[4];
    float* out = (float*)d_out;
    char* ws = (char*)d_ws;

    unsigned short* xb   = (unsigned short*)(ws);              // [4096][1024] bf16, reused as z
    unsigned short* wa_t = (unsigned short*)(ws + 8388608);    // [3072][1024]
    unsigned short* wp_t = (unsigned short*)(ws + 14680064);   // [1024][1024]
    unsigned short* qb   = (unsigned short*)(ws + 16777216);   // fragment-major Q (pre-scaled)
    unsigned short* kb   = (unsigned short*)(ws + 25165824);   // fragment-major K
    unsigned short* vb   = (unsigned short*)(ws + 33554432);   // fragment-major V
    unsigned short* zb   = xb;                                 // alias: x consumed by gemm_qkv

    cvt_kernel<<<4096, 256, 0, stream>>>(x, xb, (4096 * 1024) / 4);
    tcvt_kernel<<<dim3(96, 32), dim3(32, 8), 0, stream>>>(w_attn, wa_t, 1024, 3072);
    tcvt_kernel<<<dim3(32, 32), dim3(32, 8), 0, stream>>>(w_proj, wp_t, 1024, 1024);
    gemm_qkv<<<dim3(24, 32), 256, 0, stream>>>(xb, wa_t, b_attn, qb, kb, vb);
    attn_kernel<<<dim3(32, 64), 128, 0, stream>>>(qb, kb, vb, zb);
    gemm_proj<<<dim3(8, 32), 256, 0, stream>>>(zb, wp_t, b_proj, out);
}

// Round 12
// 121.280 us; speedup vs baseline: 1.1129x; 1.1129x over previous
//
#include <hip/hip_runtime.h>

#define B_ 2
#define S_ 2048
#define F_ 1024
#define H_ 16
#define D_ 64

typedef __bf16 bf16x8 __attribute__((ext_vector_type(8)));
typedef float f32x4 __attribute__((ext_vector_type(4)));
typedef float f32x16 __attribute__((ext_vector_type(16)));

union U8 { unsigned int u[4]; bf16x8 v; };

__device__ __forceinline__ unsigned short f2bf(float f) {
    union { float f; unsigned int u; } v;
    v.f = f;
    unsigned int r = v.u + 0x7fffu + ((v.u >> 16) & 1u);
    return (unsigned short)(r >> 16);
}

__device__ __forceinline__ unsigned int cvtpk_bf16(float lo, float hi) {
    unsigned int r;
    asm("v_cvt_pk_bf16_f32 %0, %1, %2" : "=v"(r) : "v"(lo), "v"(hi));
    return r;
}

// cross-half (lane l <-> l^32) reductions. DS-based shfl: proven correct (R4).
__device__ __forceinline__ float xhalf_max(float x) {
    return fmaxf(x, __shfl_xor(x, 32));
}
__device__ __forceinline__ float xhalf_sum(float x) {
    return x + __shfl_xor(x, 32);
}

// async global->LDS, 16B per lane. LDS dest must be wave-uniform base + lane*16.
__device__ __forceinline__ void gload16(const unsigned short* g, unsigned short* l) {
    __builtin_amdgcn_global_load_lds(
        (const __attribute__((address_space(1))) unsigned int*)g,
        (__attribute__((address_space(3))) unsigned int*)l,
        16, 0, 0);
}

// ---------- f32 -> bf16 elementwise convert (vectorized) ----------
__global__ void cvt_kernel(const float* __restrict__ in, unsigned short* __restrict__ out, int n4) {
    int i = blockIdx.x * blockDim.x + threadIdx.x;
    if (i >= n4) return;
    float4 v = reinterpret_cast<const float4*>(in)[i];
    ushort4 o;
    o.x = f2bf(v.x); o.y = f2bf(v.y); o.z = f2bf(v.z); o.w = f2bf(v.w);
    reinterpret_cast<ushort4*>(out)[i] = o;
}

// ---------- f32 [R][C] -> bf16 [C][R] transpose-convert ----------
__global__ void tcvt_kernel(const float* __restrict__ in, unsigned short* __restrict__ out, int R, int C) {
    __shared__ float t[32][33];
    int r0 = blockIdx.y << 5, c0 = blockIdx.x << 5;
    int tx = threadIdx.x, ty = threadIdx.y;
#pragma unroll
    for (int kk = 0; kk < 4; ++kk)
        t[ty + 8 * kk][tx] = in[(size_t)(r0 + ty + 8 * kk) * C + c0 + tx];
    __syncthreads();
#pragma unroll
    for (int kk = 0; kk < 4; ++kk)
        out[(size_t)(c0 + ty + 8 * kk) * R + r0 + tx] = f2bf(t[tx][ty + 8 * kk]);
}

// ---------- GEMM1: qkv = x @ w_attn + b_attn (2-phase pipelined global_load_lds; R10-proven) ----------
// q,k stored FRAGMENT-MAJOR: [bh][t=s/32][kf=d/16][lane=(s&31)|((d>>3&1)<<5)][e=d&7]
// v  stored FRAGMENT-MAJOR: [bh][jt=s/32][db=d/32][kf=(s>>4)&1][lane=(d&31)|((s>>3&1)<<5)][e=s&7]
// q pre-scaled by (1/8)*log2(e)
__global__ __launch_bounds__(256) void gemm_qkv(const unsigned short* __restrict__ A,
                                                const unsigned short* __restrict__ Bt,
                                                const float* __restrict__ bias,
                                                unsigned short* __restrict__ qo,
                                                unsigned short* __restrict__ ko,
                                                unsigned short* __restrict__ vo) {
    __shared__ __align__(16) unsigned short As[2 * 128 * 32];  // [buf][row][col]
    __shared__ __align__(16) unsigned short Bs[2 * 128 * 32];
    const int K = 1024, NT = 32;
    int m0 = blockIdx.y << 7, n0 = blockIdx.x << 7;
    int tid = threadIdx.x;
    int w = tid >> 6, l = tid & 63, lg = l >> 4, lr = l & 15;
    int wm = (w >> 1) << 6, wn = (w & 1) << 6;
    f32x4 acc[4][4] = {};

    int sr = tid >> 2, sc = (tid & 3) << 3;
    const unsigned short* Ab = A + (size_t)(m0 + sr) * K + sc;
    const unsigned short* Bb = Bt + (size_t)(n0 + sr) * K + sc;
    const size_t half = (size_t)64 * K;

    // prologue: stage K-step 0 into buffer 0
    gload16(Ab, &As[tid * 8]);
    gload16(Ab + half, &As[2048 + tid * 8]);
    gload16(Bb, &Bs[tid * 8]);
    gload16(Bb + half, &Bs[2048 + tid * 8]);
    __syncthreads();

    for (int t = 0; t < NT; ++t) {
        int cur = (t & 1) * 4096;
        if (t + 1 < NT) {
            int nxt = ((t + 1) & 1) * 4096;
            int ko2 = (t + 1) * 32;
            gload16(Ab + ko2, &As[nxt + tid * 8]);
            gload16(Ab + ko2 + half, &As[nxt + 2048 + tid * 8]);
            gload16(Bb + ko2, &Bs[nxt + tid * 8]);
            gload16(Bb + ko2 + half, &Bs[nxt + 2048 + tid * 8]);
        }
        bf16x8 af[4], bfr[4];
#pragma unroll
        for (int mi = 0; mi < 4; ++mi)
            af[mi] = *reinterpret_cast<const bf16x8*>(&As[cur + (wm + mi * 16 + lr) * 32 + (lg << 3)]);
#pragma unroll
        for (int ni = 0; ni < 4; ++ni)
            bfr[ni] = *reinterpret_cast<const bf16x8*>(&Bs[cur + (wn + ni * 16 + lr) * 32 + (lg << 3)]);
#pragma unroll
        for (int mi = 0; mi < 4; ++mi)
#pragma unroll
            for (int ni = 0; ni < 4; ++ni)
                acc[mi][ni] = __builtin_amdgcn_mfma_f32_16x16x32_bf16(af[mi], bfr[ni], acc[mi][ni], 0, 0, 0);
        __syncthreads();   // drains next-step loads (issued a full compute phase ago)
    }
#pragma unroll
    for (int mi = 0; mi < 4; ++mi) {
#pragma unroll
        for (int ni = 0; ni < 4; ++ni) {
            int col = n0 + wn + ni * 16 + lr;
            float bv = bias[col];
            int part = col >> 10, cc = col & 1023, h = cc >> 6, d = cc & 63;
            int row0 = m0 + wm + mi * 16 + (lg << 2);
            int bb = row0 >> 11, s0 = row0 & 2047;
            int bh = bb * H_ + h;
            if (part == 2) {
                int jt = s0 >> 5, db = d >> 5, kf2 = (s0 >> 4) & 1, hi2 = (s0 >> 3) & 1;
                int ll = (d & 31) | (hi2 << 5), e0 = s0 & 7;
                ushort4 pk;
                unsigned short* p = reinterpret_cast<unsigned short*>(&pk);
#pragma unroll
                for (int r = 0; r < 4; ++r) p[r] = f2bf(acc[mi][ni][r] + bv);
                *reinterpret_cast<ushort4*>(
                    &vo[(size_t)((((bh * 64 + jt) * 2 + db) * 2 + kf2)) * 512 + ll * 8 + e0]) = pk;
            } else {
                unsigned short* dst = part == 0 ? qo : ko;
                float scale = part == 0 ? 0.125f * 1.44269504f : 1.0f;
                int t2 = s0 >> 5, kf2 = d >> 4, e = d & 7;
                int lbase = ((d >> 3) & 1) << 5;
                size_t fb = (size_t)((bh * 64 + t2) * 4 + kf2) * 512 + e;
#pragma unroll
                for (int r = 0; r < 4; ++r) {
                    float vv = (acc[mi][ni][r] + bv) * scale;
                    dst[fb + (size_t)((((s0 + r) & 31) | lbase)) * 8] = f2bf(vv);
                }
            }
        }
    }
}

// ---------- GEMM2: out = z @ w_proj + b_proj (f32 out; 2-phase pipelined; R10-proven) ----------
__global__ __launch_bounds__(256) void gemm_proj(const unsigned short* __restrict__ A,
                                                 const unsigned short* __restrict__ Bt,
                                                 const float* __restrict__ bias,
                                                 float* __restrict__ out) {
    __shared__ __align__(16) unsigned short As[2 * 128 * 32];
    __shared__ __align__(16) unsigned short Bs[2 * 128 * 32];
    const int K = 1024, NT = 32;
    int m0 = blockIdx.y << 7, n0 = blockIdx.x << 7;
    int tid = threadIdx.x;
    int w = tid >> 6, l = tid & 63, lg = l >> 4, lr = l & 15;
    int wm = (w >> 1) << 6, wn = (w & 1) << 6;
    f32x4 acc[4][4] = {};

    int sr = tid >> 2, sc = (tid & 3) << 3;
    const unsigned short* Ab = A + (size_t)(m0 + sr) * K + sc;
    const unsigned short* Bb = Bt + (size_t)(n0 + sr) * K + sc;
    const size_t half = (size_t)64 * K;

    gload16(Ab, &As[tid * 8]);
    gload16(Ab + half, &As[2048 + tid * 8]);
    gload16(Bb, &Bs[tid * 8]);
    gload16(Bb + half, &Bs[2048 + tid * 8]);
    __syncthreads();

    for (int t = 0; t < NT; ++t) {
        int cur = (t & 1) * 4096;
        if (t + 1 < NT) {
            int nxt = ((t + 1) & 1) * 4096;
            int ko2 = (t + 1) * 32;
            gload16(Ab + ko2, &As[nxt + tid * 8]);
            gload16(Ab + ko2 + half, &As[nxt + 2048 + tid * 8]);
            gload16(Bb + ko2, &Bs[nxt + tid * 8]);
            gload16(Bb + ko2 + half, &Bs[nxt + 2048 + tid * 8]);
        }
        bf16x8 af[4], bfr[4];
#pragma unroll
        for (int mi = 0; mi < 4; ++mi)
            af[mi] = *reinterpret_cast<const bf16x8*>(&As[cur + (wm + mi * 16 + lr) * 32 + (lg << 3)]);
#pragma unroll
        for (int ni = 0; ni < 4; ++ni)
            bfr[ni] = *reinterpret_cast<const bf16x8*>(&Bs[cur + (wn + ni * 16 + lr) * 32 + (lg << 3)]);
#pragma unroll
        for (int mi = 0; mi < 4; ++mi)
#pragma unroll
            for (int ni = 0; ni < 4; ++ni)
                acc[mi][ni] = __builtin_amdgcn_mfma_f32_16x16x32_bf16(af[mi], bfr[ni], acc[mi][ni], 0, 0, 0);
        __syncthreads();
    }
#pragma unroll
    for (int mi = 0; mi < 4; ++mi) {
#pragma unroll
        for (int ni = 0; ni < 4; ++ni) {
            int col = n0 + wn + ni * 16 + lr;
            float bv = bias[col];
#pragma unroll
            for (int r = 0; r < 4; ++r) {
                int row = m0 + wm + mi * 16 + (lg << 2) + r;
                out[(size_t)row * F_ + col] = acc[mi][ni][r] + bv;
            }
        }
    }
}

// ---------- attention 32x32 tile: fragment-major loads, in-register softmax ----------
__device__ __forceinline__ void attn_tile32(
    const unsigned short* __restrict__ k, const unsigned short* __restrict__ v,
    int bh, int jt, bool pref, bool diag, int qcol, int hi, size_t lofs,
    const bf16x8 (&qf)[4], bf16x8 (&kcur)[4], bf16x8 (&knxt)[4],
    float &m, float &lsum, f32x16 &ot0, f32x16 &ot1)
{
    // V fragments for THIS tile: contiguous 1KB wave-loads
    bf16x8 vf[4];
    const unsigned short* vp = v + (size_t)(bh * 64 + jt) * 2048 + lofs;
#pragma unroll
    for (int i = 0; i < 4; ++i)
        vf[i] = *reinterpret_cast<const bf16x8*>(vp + i * 512);
    // K fragments for NEXT tile
    if (pref) {
        const unsigned short* kp = k + (size_t)(bh * 64 + jt + 1) * 2048 + lofs;
#pragma unroll
        for (int kf = 0; kf < 4; ++kf)
            knxt[kf] = *reinterpret_cast<const bf16x8*>(kp + kf * 512);
    }

    // S^T[k][q] = K Q^T : lane owns column q=qcol, 16 k-rows in regs
    f32x16 st = {};
#pragma unroll
    for (int kf = 0; kf < 4; ++kf)
        st = __builtin_amdgcn_mfma_f32_32x32x16_bf16(kcur[kf], qf[kf], st, 0, 0, 0);

    // causal mask: only the diagonal tile
    if (diag) {
        int qmh = qcol - 4 * hi;
#pragma unroll
        for (int r = 0; r < 16; ++r) {
            const int kbase = (r & 3) + 8 * (r >> 2);
            st[r] = (kbase > qmh) ? -1e30f : st[r];
        }
    }

    // row max: in-register tree + cross-half exchange
    float pm = st[0];
#pragma unroll
    for (int r = 1; r < 16; ++r) pm = fmaxf(pm, st[r]);
    pm = xhalf_max(pm);

    // defer-max (T13): rescale only when max grows beyond threshold (log2 domain)
    if (!__all(pm <= m + 8.0f)) {
        float mn = fmaxf(m, pm);
        float scl = exp2f(m - mn);
        m = mn;
        lsum *= scl;
        ot0 *= scl;
        ot1 *= scl;
    }

    // exp + lane-local partial sum (cross-half sum deferred to end of wave;
    // partner lanes share qcol hence share m, so deferral is exact)
    float ps = 0.f;
#pragma unroll
    for (int r = 0; r < 16; ++r) { st[r] = exp2f(st[r] - m); ps += st[r]; }
    lsum += ps;

    // pack P -> bf16 B-fragments via cvt_pk + permlane32_swap (T12; proven R4/R5)
    U8 pa0, pa1;
#pragma unroll
    for (int f = 0; f < 2; ++f) {
        unsigned int a0 = cvtpk_bf16(st[f * 8 + 0], st[f * 8 + 1]);
        unsigned int b0 = cvtpk_bf16(st[f * 8 + 4], st[f * 8 + 5]);
        asm("v_permlane32_swap_b32 %0, %1" : "+v"(a0), "+v"(b0));
        unsigned int a1 = cvtpk_bf16(st[f * 8 + 2], st[f * 8 + 3]);
        unsigned int b1 = cvtpk_bf16(st[f * 8 + 6], st[f * 8 + 7]);
        asm("v_permlane32_swap_b32 %0, %1" : "+v"(a1), "+v"(b1));
        U8& pa = f ? pa1 : pa0;
        pa.u[0] = a0; pa.u[1] = a1; pa.u[2] = b0; pa.u[3] = b1;
    }

    // O^T[d][q] += V^T P^T
    ot0 = __builtin_amdgcn_mfma_f32_32x32x16_bf16(vf[0], pa0.v, ot0, 0, 0, 0);
    ot0 = __builtin_amdgcn_mfma_f32_32x32x16_bf16(vf[1], pa1.v, ot0, 0, 0, 0);
    ot1 = __builtin_amdgcn_mfma_f32_32x32x16_bf16(vf[2], pa0.v, ot1, 0, 0, 0);
    ot1 = __builtin_amdgcn_mfma_f32_32x32x16_bf16(vf[3], pa1.v, ot1, 0, 0, 0);
}

// ---------- causal flash attention: 4-wave block, 4-way split-K, LDS merge ----------
// (256,3): VGPR cap ~170, body ~150 -> no spill (R5's failure was the (256,4)=128 cap)
__global__ __launch_bounds__(256, 3) void attn_kernel(const unsigned short* __restrict__ q,
                                                      const unsigned short* __restrict__ k,
                                                      const unsigned short* __restrict__ v,
                                                      unsigned short* __restrict__ z) {
    __shared__ __align__(16) float mbuf[3][64][36];
    int bh = blockIdx.x;
    int qt = gridDim.y - 1 - blockIdx.y;   // longest blocks dispatched first
    int q0 = qt << 5;
    int tid = threadIdx.x, w = tid >> 6, l = tid & 63;
    int qcol = l & 31, hi = l >> 5;
    size_t lofs = (size_t)l * 8;

    bf16x8 qf[4];
    {
        const unsigned short* qp = q + (size_t)(bh * 64 + qt) * 2048 + lofs;
#pragma unroll
        for (int kf = 0; kf < 4; ++kf)
            qf[kf] = *reinterpret_cast<const bf16x8*>(qp + kf * 512);
    }

    f32x16 ot0 = {}, ot1 = {};
    float m = -1e30f, lsum = 0.f;

    // contiguous k-range split across 4 waves (R5-proven formula);
    // wave 3 always owns the diagonal tile
    int ntk = qt + 1;
    int bs = ntk >> 2, rem = ntk & 3;
    int cnt = bs + ((w >= 4 - rem) ? 1 : 0);
    int start = bs * w + ((w - (4 - rem)) > 0 ? (w - (4 - rem)) : 0);
    int end = start + cnt;

    if (cnt > 0) {
        bf16x8 kA[4], kB[4];
        const unsigned short* kp = k + (size_t)(bh * 64 + start) * 2048 + lofs;
#pragma unroll
        for (int kf = 0; kf < 4; ++kf)
            kA[kf] = *reinterpret_cast<const bf16x8*>(kp + kf * 512);

        int jt = start;
        for (;;) {
            attn_tile32(k, v, bh, jt, jt + 1 < end, jt == qt, qcol, hi, lofs,
                        qf, kA, kB, m, lsum, ot0, ot1);
            if (++jt >= end) break;
            attn_tile32(k, v, bh, jt, jt + 1 < end, jt == qt, qcol, hi, lofs,
                        qf, kB, kA, m, lsum, ot0, ot1);
            if (++jt >= end) break;
        }
    }

    // full-row lsum (cross-half halves share qcol hence share m)
    lsum = xhalf_sum(lsum);

    // ---- split-K merge: waves 1-3 publish, wave 0 combines + writes ----
    if (w) {
        float* row = mbuf[w - 1][l];
        row[0] = m;
        row[1] = lsum;
        *reinterpret_cast<f32x16*>(&row[4]) = ot0;
        *reinterpret_cast<f32x16*>(&row[20]) = ot1;
    }
    __syncthreads();
    if (w == 0) {
        float mw0 = mbuf[0][l][0], mw1 = mbuf[1][l][0], mw2 = mbuf[2][l][0];
        float mm = fmaxf(fmaxf(m, mw0), fmaxf(mw1, mw2));
        float s0 = exp2f(m - mm);
        lsum *= s0; ot0 *= s0; ot1 *= s0;
#pragma unroll
        for (int i = 0; i < 3; ++i) {
            float sw = exp2f(mbuf[i][l][0] - mm);
            lsum += mbuf[i][l][1] * sw;
            f32x16 t0 = *reinterpret_cast<const f32x16*>(&mbuf[i][l][4]);
            f32x16 t1 = *reinterpret_cast<const f32x16*>(&mbuf[i][l][20]);
            ot0 += t0 * sw;
            ot1 += t1 * sw;
        }

        float inv = 1.0f / lsum;
        int b = bh >> 4, h = bh & 15;
        size_t zrow = ((size_t)(b * S_ + q0 + qcol)) * F_ + h * D_;
#pragma unroll
        for (int db = 0; db < 2; ++db) {
#pragma unroll
            for (int rq = 0; rq < 4; ++rq) {
                ushort4 pk;
                unsigned short* pp = reinterpret_cast<unsigned short*>(&pk);
#pragma unroll
                for (int i = 0; i < 4; ++i) {
                    float val = (db == 0 ? ot0[rq * 4 + i] : ot1[rq * 4 + i]) * inv;
                    pp[i] = f2bf(val);
                }
                *reinterpret_cast<ushort4*>(&z[zrow + db * 32 + rq * 8 + hi * 4]) = pk;
            }
        }
    }
}

extern "C" void kernel_launch(void* const* d_in, const int* in_sizes, int n_in,
                              void* d_out, int out_size, void* d_ws, size_t ws_size,
                              hipStream_t stream) {
    const float* x      = (const float*)d_in[0];
    const float* w_attn = (const float*)d_in[1];
    const float* b_attn = (const float*)d_in[2];
    const float* w_proj = (const float*)d_in[3];
    const float* b_proj = (const float*)d_in[4];
    float* out = (float*)d_out;
    char* ws = (char*)d_ws;

    unsigned short* xb   = (unsigned short*)(ws);              // [4096][1024] bf16, reused as z
    unsigned short* wa_t = (unsigned short*)(ws + 8388608);    // [3072][1024]
    unsigned short* wp_t = (unsigned short*)(ws + 14680064);   // [1024][1024]
    unsigned short* qb   = (unsigned short*)(ws + 16777216);   // fragment-major Q (pre-scaled)
    unsigned short* kb   = (unsigned short*)(ws + 25165824);   // fragment-major K
    unsigned short* vb   = (unsigned short*)(ws + 33554432);   // fragment-major V
    unsigned short* zb   = xb;                                 // alias: x consumed by gemm_qkv

    cvt_kernel<<<4096, 256, 0, stream>>>(x, xb, (4096 * 1024) / 4);
    tcvt_kernel<<<dim3(96, 32), dim3(32, 8), 0, stream>>>(w_attn, wa_t, 1024, 3072);
    tcvt_kernel<<<dim3(32, 32), dim3(32, 8), 0, stream>>>(w_proj, wp_t, 1024, 1024);
    gemm_qkv<<<dim3(24, 32), 256, 0, stream>>>(xb, wa_t, b_attn, qb, kb, vb);
    attn_kernel<<<dim3(32, 64), 256, 0, stream>>>(qb, kb, vb, zb);
    gemm_proj<<<dim3(8, 32), 256, 0, stream>>>(zb, wp_t, b_proj, out);
}